// Round 1
// baseline (2180.935 us; speedup 1.0000x reference)
//
#include <hip/hip_runtime.h>
#include <math.h>

// VQ: x (8,2048,1024) f32, codebook (8,1024,128) f32
// out = [quantized 16777216 f32][commit 1][codebook 1][indices 131072 (as f32)]

#define NPOS   16384      // B*T
#define GROUPS 8
#define KCODES 1024
#define DC     128
#define QSIZE  16777216   // NPOS * GROUPS * DC
#define NBLOCKS_MAIN 512

// Kernel 1: c2[g][k] = sum_d c^2  (explicit mul+add rounding, mimics XLA elementwise+reduce)
__global__ void vq_c2_kernel(const float* __restrict__ cb, float* __restrict__ c2) {
    int j = blockIdx.x * 256 + threadIdx.x;            // 0..8191 = g*1024+k
    const float* c = cb + (size_t)j * DC;
    float s = 0.f;
    #pragma unroll
    for (int d = 0; d < DC; d += 4) {
        float4 v = *reinterpret_cast<const float4*>(c + d);
        s = __fadd_rn(s, __fmul_rn(v.x, v.x));
        s = __fadd_rn(s, __fmul_rn(v.y, v.y));
        s = __fadd_rn(s, __fmul_rn(v.z, v.z));
        s = __fadd_rn(s, __fmul_rn(v.w, v.w));
    }
    c2[j] = s;
}

// Kernel 2: one thread per (position, group). xs in VGPRs; codes are wave-uniform
// loads (scalar-pipe broadcast) -> no LDS, no VMEM in hot loop. Compute-bound fp32.
__global__ __launch_bounds__(256, 2) void vq_main_kernel(
        const float* __restrict__ x, const float* __restrict__ cb,
        const float* __restrict__ c2, float* __restrict__ out,
        float* __restrict__ partials) {
    const int bid = blockIdx.x;
    const int g = bid & 7;                 // group == XCD slot: codebook slice stays in one L2
    const int p = (bid >> 3) * 256 + (int)threadIdx.x;
    const float* xp = x + (size_t)p * (GROUPS * DC) + g * DC;

    float xs[DC];                          // 128 VGPRs, all statically indexed
    #pragma unroll
    for (int d = 0; d < DC; d += 4) {
        float4 v = *reinterpret_cast<const float4*>(xp + d);
        xs[d] = v.x; xs[d+1] = v.y; xs[d+2] = v.z; xs[d+3] = v.w;
    }
    float x2 = 0.f;
    #pragma unroll
    for (int d = 0; d < DC; ++d) x2 = __fadd_rn(x2, __fmul_rn(xs[d], xs[d]));

    const float* cg  = cb + (size_t)g * KCODES * DC;
    const float* c2g = c2 + g * KCODES;

    float best = INFINITY;
    int bestk = 0;
    #pragma unroll 2
    for (int k = 0; k < KCODES; ++k) {
        const float* ck = cg + (size_t)k * DC;   // wave-uniform address
        float a0 = 0.f, a1 = 0.f;                // two chains cover FMA dep latency
        #pragma unroll
        for (int d = 0; d < 64; ++d)  a0 = fmaf(xs[d], ck[d], a0);
        #pragma unroll
        for (int d = 64; d < DC; ++d) a1 = fmaf(xs[d], ck[d], a1);
        float xc = __fadd_rn(a0, a1);
        // dist = (x2 - 2*xc) + c2  -- explicit rounding, no contraction:
        // the ~128-magnitude x2 quantizes dist to ~1.5e-5, absorbing sum-order noise
        float dist = __fadd_rn(__fsub_rn(x2, __fmul_rn(2.0f, xc)), c2g[k]);
        if (dist < best) { best = dist; bestk = k; }   // strict < => first-index ties
    }

    // Epilogue: gather chosen code, write quantized = xs + (q - xs), accumulate loss
    const float* q = cg + (size_t)bestk * DC;
    float* op = out + (size_t)p * (GROUPS * DC) + g * DC;
    float lsum = 0.f;
    #pragma unroll
    for (int d = 0; d < DC; d += 4) {
        float4 qv = *reinterpret_cast<const float4*>(q + d);
        float4 ov; float e;
        e = __fsub_rn(xs[d+0], qv.x); lsum = __fadd_rn(lsum, __fmul_rn(e, e));
        ov.x = __fadd_rn(xs[d+0], __fsub_rn(qv.x, xs[d+0]));
        e = __fsub_rn(xs[d+1], qv.y); lsum = __fadd_rn(lsum, __fmul_rn(e, e));
        ov.y = __fadd_rn(xs[d+1], __fsub_rn(qv.y, xs[d+1]));
        e = __fsub_rn(xs[d+2], qv.z); lsum = __fadd_rn(lsum, __fmul_rn(e, e));
        ov.z = __fadd_rn(xs[d+2], __fsub_rn(qv.z, xs[d+2]));
        e = __fsub_rn(xs[d+3], qv.w); lsum = __fadd_rn(lsum, __fmul_rn(e, e));
        ov.w = __fadd_rn(xs[d+3], __fsub_rn(qv.w, xs[d+3]));
        *reinterpret_cast<float4*>(op + d) = ov;
    }
    // indices (B,T,G) as float32 (JAX concat promotes int32+f32 -> f32)
    out[(size_t)QSIZE + 2 + (size_t)p * GROUPS + g] = (float)bestk;

    // deterministic block partial for the losses
    #pragma unroll
    for (int off = 32; off > 0; off >>= 1)
        lsum += __shfl_down(lsum, off, 64);
    __shared__ float wsum[4];
    if ((threadIdx.x & 63) == 0) wsum[threadIdx.x >> 6] = lsum;
    __syncthreads();
    if (threadIdx.x == 0)
        partials[bid] = __fadd_rn(__fadd_rn(wsum[0], wsum[1]),
                                  __fadd_rn(wsum[2], wsum[3]));
}

// Kernel 3: deterministic double-precision reduction of 512 block partials
__global__ void vq_loss_kernel(const float* __restrict__ partials, float* __restrict__ out) {
    __shared__ double sd[256];
    int t = threadIdx.x;
    sd[t] = (double)partials[t] + (double)partials[t + 256];
    __syncthreads();
    for (int off = 128; off > 0; off >>= 1) {
        if (t < off) sd[t] += sd[t + off];
        __syncthreads();
    }
    if (t == 0) {
        float loss = (float)(sd[0] / 16777216.0);
        out[QSIZE]     = loss;   // commitment_loss
        out[QSIZE + 1] = loss;   // codebook_loss (bit-identical in reference)
    }
}

extern "C" void kernel_launch(void* const* d_in, const int* in_sizes, int n_in,
                              void* d_out, int out_size, void* d_ws, size_t ws_size,
                              hipStream_t stream) {
    const float* x  = (const float*)d_in[0];
    const float* cb = (const float*)d_in[1];
    float* out = (float*)d_out;
    float* partials = (float*)d_ws;               // 512 floats
    float* c2       = partials + NBLOCKS_MAIN;    // 8192 floats
    vq_c2_kernel<<<32, 256, 0, stream>>>(cb, c2);
    vq_main_kernel<<<NBLOCKS_MAIN, 256, 0, stream>>>(x, cb, c2, out, partials);
    vq_loss_kernel<<<1, 256, 0, stream>>>(partials, out);
}

// Round 7
// 1118.969 us; speedup vs baseline: 1.9491x; 1.9491x over previous
//
#include <hip/hip_runtime.h>
#include <math.h>

// VQ: x (8,2048,1024) f32, codebook (8,1024,128) f32
// out = [quantized 16777216 f32][commit 1][codebook 1][indices 131072 (as f32)]
//
// Pipeline: prep (c2 + bf16 hi/lo codebook) -> MFMA search (3-pass bf16 split,
// packed top-2 margin tracking) -> cleanup (exact fp32 rescan of risky rows,
// bit-identical to round-1 formula) -> epilogue (gather/write/loss) -> loss.

typedef __attribute__((ext_vector_type(8))) short short8v;
typedef __attribute__((ext_vector_type(4))) float f32x4;

#define NPOS   16384
#define GROUPS 8
#define KCODES 1024
#define DC     128
#define QSIZE  16777216
#define MARGIN 2.5e-3f

__device__ inline unsigned rne_bf16(float f) {
  unsigned u = __float_as_uint(f);
  return (u + 0x7FFFu + ((u >> 16) & 1u)) >> 16;
}
__device__ inline unsigned umin32(unsigned a, unsigned b) { return a < b ? a : b; }
__device__ inline unsigned umax32(unsigned a, unsigned b) { return a > b ? a : b; }

// ---------------- prep: c2 (exact, round-1 order) + bf16 hi/lo codebook ----------------
__global__ void vq_prep_kernel(const float* __restrict__ cb, unsigned* __restrict__ cbh,
                               unsigned* __restrict__ cbl, float* __restrict__ c2) {
  int j = blockIdx.x * 256 + threadIdx.x;            // 8192 rows (g*1024+k)
  const float* c = cb + (size_t)j * DC;
  unsigned* Hp = cbh + j * 64;
  unsigned* Lp = cbl + j * 64;
  float s = 0.f;
  #pragma unroll
  for (int d = 0; d < DC; d += 4) {
    float4 v = *reinterpret_cast<const float4*>(c + d);
    s = __fadd_rn(s, __fmul_rn(v.x, v.x));
    s = __fadd_rn(s, __fmul_rn(v.y, v.y));
    s = __fadd_rn(s, __fmul_rn(v.z, v.z));
    s = __fadd_rn(s, __fmul_rn(v.w, v.w));
    float fv[4] = {v.x, v.y, v.z, v.w};
    unsigned hb[4], lb[4];
    #pragma unroll
    for (int t = 0; t < 4; ++t) {
      hb[t] = rne_bf16(fv[t]);
      float r = __fsub_rn(fv[t], __uint_as_float(hb[t] << 16));
      lb[t] = rne_bf16(r);
    }
    Hp[d/2]     = hb[0] | (hb[1] << 16);
    Hp[d/2 + 1] = hb[2] | (hb[3] << 16);
    Lp[d/2]     = lb[0] | (lb[1] << 16);
    Lp[d/2 + 1] = lb[2] | (lb[3] << 16);
  }
  c2[j] = s;
}

// ---------------- phase A: MFMA search ----------------
// Block: 64 positions x one group, 4 waves x 256 codes each.
// A-frag: lane holds A[(lane&15)+16*mb][kb*32+(lane>>4)*8+j]; B-frag same rows=codes.
// C/D: col=lane&15 (code), row=(lane>>4)*4+reg (+16*mb).  [guide §3, m89/m91]
__global__ __launch_bounds__(256, 2) void vq_search_kernel(
    const float* __restrict__ x, const unsigned short* __restrict__ cbh,
    const unsigned short* __restrict__ cbl, const float* __restrict__ c2,
    unsigned* __restrict__ results) {
  const int bid = blockIdx.x;
  const int g = bid & 7;                       // group == XCD slot
  const int pb = (bid >> 3) * 64;
  const int tid = (int)threadIdx.x;
  const int wave = tid >> 6, lane = tid & 63;
  const int lr = lane & 15, lq = lane >> 4;

  // ---- A-tile fragments (hi/lo bf16), held in VGPRs for the whole kernel (128 VGPR)
  short8v ah[4][4], al[4][4];
  #pragma unroll
  for (int mb = 0; mb < 4; ++mb) {
    #pragma unroll
    for (int kb = 0; kb < 4; ++kb) {
      const float* src = x + (size_t)(pb + mb*16 + lr) * (GROUPS*DC) + g*DC + kb*32 + lq*8;
      float4 f0 = *reinterpret_cast<const float4*>(src);
      float4 f1 = *reinterpret_cast<const float4*>(src + 4);
      float fv[8] = {f0.x, f0.y, f0.z, f0.w, f1.x, f1.y, f1.z, f1.w};
      short8v h8, l8;
      #pragma unroll
      for (int jj = 0; jj < 8; ++jj) {
        unsigned hb = rne_bf16(fv[jj]);
        float r = __fsub_rn(fv[jj], __uint_as_float(hb << 16));
        unsigned lb = rne_bf16(r);
        h8[jj] = (short)hb; l8[jj] = (short)lb;
      }
      ah[mb][kb] = h8; al[mb][kb] = l8;
    }
  }

  const unsigned short* cbhg = cbh + (size_t)g * KCODES * DC;
  const unsigned short* cblg = cbl + (size_t)g * KCODES * DC;
  const float* c2g = c2 + g * KCODES;
  const int kw = wave * 256;

  unsigned d1[4][4], d2[4][4];
  #pragma unroll
  for (int mb = 0; mb < 4; ++mb)
    #pragma unroll
    for (int r = 0; r < 4; ++r) { d1[mb][r] = 0xFFFFFFFFu; d2[mb][r] = 0xFFFFFFFFu; }

  // 16 chunks of 16 codes; single-buffered B-frags (fits 256-VGPR cap at 2 blk/CU);
  // L2 latency per chunk is covered by the co-resident block's waves (m114).
  #pragma unroll 1
  for (int ch = 0; ch < 16; ++ch) {
    short8v bh[4], bl[4];
    const unsigned short* p = cbhg + (size_t)(kw + ch*16 + lr) * DC + lq*8;
    const unsigned short* q = cblg + (size_t)(kw + ch*16 + lr) * DC + lq*8;
    #pragma unroll
    for (int kb = 0; kb < 4; ++kb) {
      bh[kb] = *reinterpret_cast<const short8v*>(p + kb*32);
      bl[kb] = *reinterpret_cast<const short8v*>(q + kb*32);
    }
    const float c2v = c2g[kw + ch*16 + lr];
    f32x4 acc[4] = {{0,0,0,0},{0,0,0,0},{0,0,0,0},{0,0,0,0}};
    #pragma unroll
    for (int kb = 0; kb < 4; ++kb) {
      #pragma unroll
      for (int mb = 0; mb < 4; ++mb) {
        acc[mb] = __builtin_amdgcn_mfma_f32_16x16x32_bf16(ah[mb][kb], bh[kb], acc[mb], 0, 0, 0);
        acc[mb] = __builtin_amdgcn_mfma_f32_16x16x32_bf16(al[mb][kb], bh[kb], acc[mb], 0, 0, 0);
        acc[mb] = __builtin_amdgcn_mfma_f32_16x16x32_bf16(ah[mb][kb], bl[kb], acc[mb], 0, 0, 0);
      }
    }
    const unsigned kpack = (unsigned)(kw + ch*16 + lr);
    #pragma unroll
    for (int mb = 0; mb < 4; ++mb) {
      #pragma unroll
      for (int r = 0; r < 4; ++r) {
        // score+4 = (c2 - 2*xc) + 4 stays positive (|xc| would need ~9 sigma to break)
        float sp = __fadd_rn(fmaf(acc[mb][r], -2.0f, c2v), 4.0f);
        unsigned u = (__float_as_uint(sp) & 0xFFFFFC00u) | kpack;
        unsigned m = umax32(u, d1[mb][r]);
        d2[mb][r] = umin32(d2[mb][r], m);
        d1[mb][r] = umin32(d1[mb][r], u);
      }
    }
  }

  // ---- cross-lane reduce (lanes sharing lq cover the same rows, cols differ)
  #pragma unroll
  for (int mb = 0; mb < 4; ++mb) {
    #pragma unroll
    for (int r = 0; r < 4; ++r) {
      #pragma unroll
      for (int xm = 1; xm < 16; xm <<= 1) {
        unsigned o1 = __shfl_xor(d1[mb][r], xm, 64);
        unsigned o2 = __shfl_xor(d2[mb][r], xm, 64);
        unsigned m = umax32(o1, d1[mb][r]);
        d2[mb][r] = umin32(umin32(d2[mb][r], o2), m);
        d1[mb][r] = umin32(d1[mb][r], o1);
      }
    }
  }
  __shared__ unsigned lred[4][64][2];
  if (lr == 0) {
    #pragma unroll
    for (int mb = 0; mb < 4; ++mb) {
      #pragma unroll
      for (int r = 0; r < 4; ++r) {
        int row = lq*4 + r + 16*mb;
        lred[wave][row][0] = d1[mb][r];
        lred[wave][row][1] = d2[mb][r];
      }
    }
  }
  __syncthreads();
  if (tid < 64) {
    unsigned m1 = 0xFFFFFFFFu, m2 = 0xFFFFFFFFu;
    #pragma unroll
    for (int w = 0; w < 4; ++w) {
      unsigned a = lred[w][tid][0], b = lred[w][tid][1];
      unsigned t = umax32(m1, a);
      m2 = umin32(umin32(m2, b), t);
      m1 = umin32(m1, a);
    }
    float f1 = __uint_as_float(m1 & 0xFFFFFC00u);
    float f2 = __uint_as_float(m2 & 0xFFFFFC00u);
    unsigned risky = (__fsub_rn(f2, f1) < MARGIN) ? 0x80000000u : 0u;
    results[(size_t)(pb + tid) * GROUPS + g] = (m1 & 1023u) | risky;
  }
}

// ---------------- cleanup: exact fp32 rescan of risky rows (block-cooperative) ----------------
__global__ void vq_cleanup_kernel(const float* __restrict__ x, const float* __restrict__ cb,
                                  const float* __restrict__ c2, unsigned* __restrict__ results) {
  const int bid = blockIdx.x;
  const int g = bid & 7;
  const int p0 = (bid >> 3) * 256;
  const int tid = (int)threadIdx.x;
  __shared__ int cnt;
  __shared__ int rl[256];
  __shared__ float xrow[DC];
  __shared__ unsigned long long red[256];
  if (tid == 0) cnt = 0;
  __syncthreads();
  unsigned rv = results[(size_t)(p0 + tid) * GROUPS + g];
  if (rv & 0x80000000u) { int i = atomicAdd(&cnt, 1); rl[i] = p0 + tid; }
  __syncthreads();
  const int n = cnt;
  const float* cg = cb + (size_t)g * KCODES * DC;
  const float* c2g = c2 + g * KCODES;
  for (int i = 0; i < n; ++i) {
    const int pr = rl[i];
    if (tid < DC) xrow[tid] = x[(size_t)pr * (GROUPS*DC) + g*DC + tid];
    __syncthreads();
    float x2 = 0.f;                      // identical op order to round-1
    #pragma unroll
    for (int d = 0; d < DC; ++d) x2 = __fadd_rn(x2, __fmul_rn(xrow[d], xrow[d]));
    unsigned long long best = ~0ull;
    #pragma unroll 1
    for (int kk = 0; kk < 4; ++kk) {
      const int k = tid*4 + kk;          // 256 threads x 4 = 1024 codes
      const float* ck = cg + (size_t)k * DC;
      float a0 = 0.f, a1 = 0.f;          // identical two-chain split to round-1
      #pragma unroll
      for (int d = 0; d < 64; ++d)  a0 = fmaf(xrow[d], ck[d], a0);
      #pragma unroll
      for (int d = 64; d < DC; ++d) a1 = fmaf(xrow[d], ck[d], a1);
      float xc = __fadd_rn(a0, a1);
      float dist = __fadd_rn(__fsub_rn(x2, __fmul_rn(2.0f, xc)), c2g[k]);
      unsigned long long key = ((unsigned long long)__float_as_uint(dist) << 32) | (unsigned)k;
      if (key < best) best = key;        // dist>0 => bits monotone; ties -> smaller k
    }
    red[tid] = best;
    __syncthreads();
    for (int off = 128; off > 0; off >>= 1) {
      if (tid < off) { if (red[tid + off] < red[tid]) red[tid] = red[tid + off]; }
      __syncthreads();
    }
    if (tid == 0) results[(size_t)pr * GROUPS + g] = (unsigned)(red[0] & 1023ull);
    __syncthreads();
  }
}

// ---------------- epilogue: gather/write/loss (round-1 code minus the k-loop) ----------------
__global__ __launch_bounds__(256, 2) void vq_epilogue_kernel(
    const float* __restrict__ x, const float* __restrict__ cb,
    const unsigned* __restrict__ results, float* __restrict__ out,
    float* __restrict__ partials) {
  const int bid = blockIdx.x;
  const int g = bid & 7;
  const int p = (bid >> 3) * 256 + (int)threadIdx.x;
  const float* xp = x + (size_t)p * (GROUPS*DC) + g*DC;
  float xs[DC];
  #pragma unroll
  for (int d = 0; d < DC; d += 4) {
    float4 v = *reinterpret_cast<const float4*>(xp + d);
    xs[d] = v.x; xs[d+1] = v.y; xs[d+2] = v.z; xs[d+3] = v.w;
  }
  const int bestk = (int)(results[(size_t)p * GROUPS + g] & 1023u);
  const float* q = cb + (size_t)g * KCODES * DC + (size_t)bestk * DC;
  float* op = out + (size_t)p * (GROUPS*DC) + g*DC;
  float lsum = 0.f;
  #pragma unroll
  for (int d = 0; d < DC; d += 4) {
    float4 qv = *reinterpret_cast<const float4*>(q + d);
    float4 ov; float e;
    e = __fsub_rn(xs[d+0], qv.x); lsum = __fadd_rn(lsum, __fmul_rn(e, e));
    ov.x = __fadd_rn(xs[d+0], __fsub_rn(qv.x, xs[d+0]));
    e = __fsub_rn(xs[d+1], qv.y); lsum = __fadd_rn(lsum, __fmul_rn(e, e));
    ov.y = __fadd_rn(xs[d+1], __fsub_rn(qv.y, xs[d+1]));
    e = __fsub_rn(xs[d+2], qv.z); lsum = __fadd_rn(lsum, __fmul_rn(e, e));
    ov.z = __fadd_rn(xs[d+2], __fsub_rn(qv.z, xs[d+2]));
    e = __fsub_rn(xs[d+3], qv.w); lsum = __fadd_rn(lsum, __fmul_rn(e, e));
    ov.w = __fadd_rn(xs[d+3], __fsub_rn(qv.w, xs[d+3]));
    *reinterpret_cast<float4*>(op + d) = ov;
  }
  out[(size_t)QSIZE + 2 + (size_t)p * GROUPS + g] = (float)bestk;

  #pragma unroll
  for (int off = 32; off > 0; off >>= 1)
    lsum += __shfl_down(lsum, off, 64);
  __shared__ float wsum[4];
  if ((threadIdx.x & 63) == 0) wsum[threadIdx.x >> 6] = lsum;
  __syncthreads();
  if (threadIdx.x == 0)
    partials[bid] = __fadd_rn(__fadd_rn(wsum[0], wsum[1]),
                              __fadd_rn(wsum[2], wsum[3]));
}

// ---------------- loss: deterministic double reduction ----------------
__global__ void vq_loss_kernel(const float* __restrict__ partials, float* __restrict__ out) {
  __shared__ double sd[256];
  int t = threadIdx.x;
  sd[t] = (double)partials[t] + (double)partials[t + 256];
  __syncthreads();
  for (int off = 128; off > 0; off >>= 1) {
    if (t < off) sd[t] += sd[t + off];
    __syncthreads();
  }
  if (t == 0) {
    float loss = (float)(sd[0] / 16777216.0);
    out[QSIZE]     = loss;
    out[QSIZE + 1] = loss;
  }
}

// ---------------- round-1 fallback (ws too small) ----------------
__global__ __launch_bounds__(256, 2) void vq_main_kernel(
    const float* __restrict__ x, const float* __restrict__ cb,
    const float* __restrict__ c2, float* __restrict__ out,
    float* __restrict__ partials) {
  const int bid = blockIdx.x;
  const int g = bid & 7;
  const int p = (bid >> 3) * 256 + (int)threadIdx.x;
  const float* xp = x + (size_t)p * (GROUPS*DC) + g*DC;
  float xs[DC];
  #pragma unroll
  for (int d = 0; d < DC; d += 4) {
    float4 v = *reinterpret_cast<const float4*>(xp + d);
    xs[d] = v.x; xs[d+1] = v.y; xs[d+2] = v.z; xs[d+3] = v.w;
  }
  float x2 = 0.f;
  #pragma unroll
  for (int d = 0; d < DC; ++d) x2 = __fadd_rn(x2, __fmul_rn(xs[d], xs[d]));
  const float* cg  = cb + (size_t)g * KCODES * DC;
  const float* c2g = c2 + g * KCODES;
  float best = INFINITY;
  int bestk = 0;
  #pragma unroll 2
  for (int k = 0; k < KCODES; ++k) {
    const float* ck = cg + (size_t)k * DC;
    float a0 = 0.f, a1 = 0.f;
    #pragma unroll
    for (int d = 0; d < 64; ++d)  a0 = fmaf(xs[d], ck[d], a0);
    #pragma unroll
    for (int d = 64; d < DC; ++d) a1 = fmaf(xs[d], ck[d], a1);
    float xc = __fadd_rn(a0, a1);
    float dist = __fadd_rn(__fsub_rn(x2, __fmul_rn(2.0f, xc)), c2g[k]);
    if (dist < best) { best = dist; bestk = k; }
  }
  const float* q = cg + (size_t)bestk * DC;
  float* op = out + (size_t)p * (GROUPS*DC) + g*DC;
  float lsum = 0.f;
  #pragma unroll
  for (int d = 0; d < DC; d += 4) {
    float4 qv = *reinterpret_cast<const float4*>(q + d);
    float4 ov; float e;
    e = __fsub_rn(xs[d+0], qv.x); lsum = __fadd_rn(lsum, __fmul_rn(e, e));
    ov.x = __fadd_rn(xs[d+0], __fsub_rn(qv.x, xs[d+0]));
    e = __fsub_rn(xs[d+1], qv.y); lsum = __fadd_rn(lsum, __fmul_rn(e, e));
    ov.y = __fadd_rn(xs[d+1], __fsub_rn(qv.y, xs[d+1]));
    e = __fsub_rn(xs[d+2], qv.z); lsum = __fadd_rn(lsum, __fmul_rn(e, e));
    ov.z = __fadd_rn(xs[d+2], __fsub_rn(qv.z, xs[d+2]));
    e = __fsub_rn(xs[d+3], qv.w); lsum = __fadd_rn(lsum, __fmul_rn(e, e));
    ov.w = __fadd_rn(xs[d+3], __fsub_rn(qv.w, xs[d+3]));
    *reinterpret_cast<float4*>(op + d) = ov;
  }
  out[(size_t)QSIZE + 2 + (size_t)p * GROUPS + g] = (float)bestk;
  #pragma unroll
  for (int off = 32; off > 0; off >>= 1)
    lsum += __shfl_down(lsum, off, 64);
  __shared__ float wsum[4];
  if ((threadIdx.x & 63) == 0) wsum[threadIdx.x >> 6] = lsum;
  __syncthreads();
  if (threadIdx.x == 0)
    partials[bid] = __fadd_rn(__fadd_rn(wsum[0], wsum[1]),
                              __fadd_rn(wsum[2], wsum[3]));
}

__global__ void vq_c2_kernel(const float* __restrict__ cb, float* __restrict__ c2) {
  int j = blockIdx.x * 256 + threadIdx.x;
  const float* c = cb + (size_t)j * DC;
  float s = 0.f;
  #pragma unroll
  for (int d = 0; d < DC; d += 4) {
    float4 v = *reinterpret_cast<const float4*>(c + d);
    s = __fadd_rn(s, __fmul_rn(v.x, v.x));
    s = __fadd_rn(s, __fmul_rn(v.y, v.y));
    s = __fadd_rn(s, __fmul_rn(v.z, v.z));
    s = __fadd_rn(s, __fmul_rn(v.w, v.w));
  }
  c2[j] = s;
}

extern "C" void kernel_launch(void* const* d_in, const int* in_sizes, int n_in,
                              void* d_out, int out_size, void* d_ws, size_t ws_size,
                              hipStream_t stream) {
  const float* x  = (const float*)d_in[0];
  const float* cb = (const float*)d_in[1];
  float* out = (float*)d_out;
  float* partials = (float*)d_ws;                         // 512 f32
  float* c2       = partials + 512;                       // 8192 f32
  unsigned* cbh   = (unsigned*)(c2 + 8192);               // 524288 u32 (2 MB)
  unsigned* cbl   = cbh + 524288;                         // 524288 u32 (2 MB)
  unsigned* results = cbl + 524288;                       // 131072 u32
  const size_t need = (512 + 8192) * 4 + (size_t)524288 * 4 * 2 + (size_t)131072 * 4;
  if (ws_size >= need) {
    vq_prep_kernel<<<32, 256, 0, stream>>>(cb, cbh, cbl, c2);
    vq_search_kernel<<<2048, 256, 0, stream>>>(
        x, (const unsigned short*)cbh, (const unsigned short*)cbl, c2, results);
    vq_cleanup_kernel<<<512, 256, 0, stream>>>(x, cb, c2, results);
    vq_epilogue_kernel<<<512, 256, 0, stream>>>(x, cb, results, out, partials);
    vq_loss_kernel<<<1, 256, 0, stream>>>(partials, out);
  } else {
    vq_c2_kernel<<<32, 256, 0, stream>>>(cb, c2);
    vq_main_kernel<<<512, 256, 0, stream>>>(x, cb, c2, out, partials);
    vq_loss_kernel<<<1, 256, 0, stream>>>(partials, out);
  }
}

// Round 9
// 713.895 us; speedup vs baseline: 3.0550x; 1.5674x over previous
//
#include <hip/hip_runtime.h>
#include <math.h>

// VQ: x (8,2048,1024) f32, codebook (8,1024,128) f32
// out = [quantized 16777216 f32][commit 1][codebook 1][indices 131072 (as f32)]
//
// Pipeline: prep (c2 + bf16 hi/lo codebook + transposed cbT) -> MFMA search
// (3-pass bf16 split, packed top-2 margin tracking) -> cleanup (exact fp32
// rescan of risky rows via d-major cbT float4 reads: 1x cache-line amp) ->
// epilogue (gather/write/loss) -> loss.

typedef __attribute__((ext_vector_type(8))) short short8v;
typedef __attribute__((ext_vector_type(4))) float f32x4;

#define NPOS   16384
#define GROUPS 8
#define KCODES 1024
#define DC     128
#define QSIZE  16777216
// bound: 3-pass bf16 dist err <= ~6e-5; pack quant < 4.9e-4 => unsafe rows
// have masked gap < 6.1e-4. 1.0e-3 keeps 60% headroom. (was 2.5e-3)
#define MARGIN 1.0e-3f

__device__ inline unsigned rne_bf16(float f) {
  unsigned u = __float_as_uint(f);
  return (u + 0x7FFFu + ((u >> 16) & 1u)) >> 16;
}
__device__ inline unsigned umin32(unsigned a, unsigned b) { return a < b ? a : b; }
__device__ inline unsigned umax32(unsigned a, unsigned b) { return a > b ? a : b; }

// ---------------- prep: c2 (exact) + bf16 hi/lo codebook + d-major cbT ----------------
__global__ void vq_prep_kernel(const float* __restrict__ cb, unsigned* __restrict__ cbh,
                               unsigned* __restrict__ cbl, float* __restrict__ c2,
                               float* __restrict__ cbT) {
  int j = blockIdx.x * 256 + threadIdx.x;            // 8192 rows (g*1024+k)
  const int g = j >> 10, k = j & 1023;
  const float* c = cb + (size_t)j * DC;
  unsigned* Hp = cbh + j * 64;
  unsigned* Lp = cbl + j * 64;
  float s = 0.f;
  #pragma unroll
  for (int d = 0; d < DC; d += 4) {
    float4 v = *reinterpret_cast<const float4*>(c + d);
    s = __fadd_rn(s, __fmul_rn(v.x, v.x));
    s = __fadd_rn(s, __fmul_rn(v.y, v.y));
    s = __fadd_rn(s, __fmul_rn(v.z, v.z));
    s = __fadd_rn(s, __fmul_rn(v.w, v.w));
    float fv[4] = {v.x, v.y, v.z, v.w};
    unsigned hb[4], lb[4];
    #pragma unroll
    for (int t = 0; t < 4; ++t) {
      hb[t] = rne_bf16(fv[t]);
      float r = __fsub_rn(fv[t], __uint_as_float(hb[t] << 16));
      lb[t] = rne_bf16(r);
      // transposed copy: cbT[(g*128 + d)*1024 + k]; wave lanes share g, k
      // consecutive -> coalesced 256B stores per d
      cbT[(size_t)(g * DC + d + t) * KCODES + k] = fv[t];
    }
    Hp[d/2]     = hb[0] | (hb[1] << 16);
    Hp[d/2 + 1] = hb[2] | (hb[3] << 16);
    Lp[d/2]     = lb[0] | (lb[1] << 16);
    Lp[d/2 + 1] = lb[2] | (lb[3] << 16);
  }
  c2[j] = s;
}

// ---------------- phase A: MFMA search ----------------
// Block: 64 positions x one group, 4 waves x 256 codes each.
// A-frag: lane holds A[(lane&15)+16*mb][kb*32+(lane>>4)*8+j]; B-frag same rows=codes.
// C/D: col=lane&15 (code), row=(lane>>4)*4+reg (+16*mb).  [guide §3, m89/m91]
__global__ __launch_bounds__(256, 2) void vq_search_kernel(
    const float* __restrict__ x, const unsigned short* __restrict__ cbh,
    const unsigned short* __restrict__ cbl, const float* __restrict__ c2,
    unsigned* __restrict__ results) {
  const int bid = blockIdx.x;
  const int g = bid & 7;                       // group == XCD slot
  const int pb = (bid >> 3) * 64;
  const int tid = (int)threadIdx.x;
  const int wave = tid >> 6, lane = tid & 63;
  const int lr = lane & 15, lq = lane >> 4;

  short8v ah[4][4], al[4][4];
  #pragma unroll
  for (int mb = 0; mb < 4; ++mb) {
    #pragma unroll
    for (int kb = 0; kb < 4; ++kb) {
      const float* src = x + (size_t)(pb + mb*16 + lr) * (GROUPS*DC) + g*DC + kb*32 + lq*8;
      float4 f0 = *reinterpret_cast<const float4*>(src);
      float4 f1 = *reinterpret_cast<const float4*>(src + 4);
      float fv[8] = {f0.x, f0.y, f0.z, f0.w, f1.x, f1.y, f1.z, f1.w};
      short8v h8, l8;
      #pragma unroll
      for (int jj = 0; jj < 8; ++jj) {
        unsigned hb = rne_bf16(fv[jj]);
        float r = __fsub_rn(fv[jj], __uint_as_float(hb << 16));
        unsigned lb = rne_bf16(r);
        h8[jj] = (short)hb; l8[jj] = (short)lb;
      }
      ah[mb][kb] = h8; al[mb][kb] = l8;
    }
  }

  const unsigned short* cbhg = cbh + (size_t)g * KCODES * DC;
  const unsigned short* cblg = cbl + (size_t)g * KCODES * DC;
  const float* c2g = c2 + g * KCODES;
  const int kw = wave * 256;

  unsigned d1[4][4], d2[4][4];
  #pragma unroll
  for (int mb = 0; mb < 4; ++mb)
    #pragma unroll
    for (int r = 0; r < 4; ++r) { d1[mb][r] = 0xFFFFFFFFu; d2[mb][r] = 0xFFFFFFFFu; }

  #pragma unroll 1
  for (int ch = 0; ch < 16; ++ch) {
    short8v bh[4], bl[4];
    const unsigned short* p = cbhg + (size_t)(kw + ch*16 + lr) * DC + lq*8;
    const unsigned short* q = cblg + (size_t)(kw + ch*16 + lr) * DC + lq*8;
    #pragma unroll
    for (int kb = 0; kb < 4; ++kb) {
      bh[kb] = *reinterpret_cast<const short8v*>(p + kb*32);
      bl[kb] = *reinterpret_cast<const short8v*>(q + kb*32);
    }
    const float c2v = c2g[kw + ch*16 + lr];
    f32x4 acc[4] = {{0,0,0,0},{0,0,0,0},{0,0,0,0},{0,0,0,0}};
    #pragma unroll
    for (int kb = 0; kb < 4; ++kb) {
      #pragma unroll
      for (int mb = 0; mb < 4; ++mb) {
        acc[mb] = __builtin_amdgcn_mfma_f32_16x16x32_bf16(ah[mb][kb], bh[kb], acc[mb], 0, 0, 0);
        acc[mb] = __builtin_amdgcn_mfma_f32_16x16x32_bf16(al[mb][kb], bh[kb], acc[mb], 0, 0, 0);
        acc[mb] = __builtin_amdgcn_mfma_f32_16x16x32_bf16(ah[mb][kb], bl[kb], acc[mb], 0, 0, 0);
      }
    }
    const unsigned kpack = (unsigned)(kw + ch*16 + lr);
    #pragma unroll
    for (int mb = 0; mb < 4; ++mb) {
      #pragma unroll
      for (int r = 0; r < 4; ++r) {
        float sp = __fadd_rn(fmaf(acc[mb][r], -2.0f, c2v), 4.0f);
        unsigned u = (__float_as_uint(sp) & 0xFFFFFC00u) | kpack;
        unsigned m = umax32(u, d1[mb][r]);
        d2[mb][r] = umin32(d2[mb][r], m);
        d1[mb][r] = umin32(d1[mb][r], u);
      }
    }
  }

  #pragma unroll
  for (int mb = 0; mb < 4; ++mb) {
    #pragma unroll
    for (int r = 0; r < 4; ++r) {
      #pragma unroll
      for (int xm = 1; xm < 16; xm <<= 1) {
        unsigned o1 = __shfl_xor(d1[mb][r], xm, 64);
        unsigned o2 = __shfl_xor(d2[mb][r], xm, 64);
        unsigned m = umax32(o1, d1[mb][r]);
        d2[mb][r] = umin32(umin32(d2[mb][r], o2), m);
        d1[mb][r] = umin32(d1[mb][r], o1);
      }
    }
  }
  __shared__ unsigned lred[4][64][2];
  if (lr == 0) {
    #pragma unroll
    for (int mb = 0; mb < 4; ++mb) {
      #pragma unroll
      for (int r = 0; r < 4; ++r) {
        int row = lq*4 + r + 16*mb;
        lred[wave][row][0] = d1[mb][r];
        lred[wave][row][1] = d2[mb][r];
      }
    }
  }
  __syncthreads();
  if (tid < 64) {
    unsigned m1 = 0xFFFFFFFFu, m2 = 0xFFFFFFFFu;
    #pragma unroll
    for (int w = 0; w < 4; ++w) {
      unsigned a = lred[w][tid][0], b = lred[w][tid][1];
      unsigned t = umax32(m1, a);
      m2 = umin32(umin32(m2, b), t);
      m1 = umin32(m1, a);
    }
    float f1 = __uint_as_float(m1 & 0xFFFFFC00u);
    float f2 = __uint_as_float(m2 & 0xFFFFFC00u);
    unsigned risky = (__fsub_rn(f2, f1) < MARGIN) ? 0x80000000u : 0u;
    results[(size_t)(pb + tid) * GROUPS + g] = (m1 & 1023u) | risky;
  }
}

// ---------------- cleanup: exact fp32 rescan of risky rows, COALESCED ----------------
// thread t owns codes 4t..4t+3; cbT is d-major so at fixed d the wave reads
// 64 consecutive float4 = contiguous 1KB (1x cache-line amplification; was 32x).
// Per-code op order is bit-identical to the round-1 formula (absmax 0.0 proven).
__global__ void vq_cleanup_kernel(const float* __restrict__ x, const float* __restrict__ cbT,
                                  const float* __restrict__ c2, unsigned* __restrict__ results) {
  const int bid = blockIdx.x;
  const int g = bid & 7;
  const int p0 = (bid >> 3) * 256;
  const int tid = (int)threadIdx.x;
  __shared__ int cnt;
  __shared__ int rl[256];
  __shared__ float xrow[DC];
  __shared__ unsigned long long red[256];
  if (tid == 0) cnt = 0;
  __syncthreads();
  unsigned rv = results[(size_t)(p0 + tid) * GROUPS + g];
  if (rv & 0x80000000u) { int i = atomicAdd(&cnt, 1); rl[i] = p0 + tid; }
  __syncthreads();
  const int n = cnt;
  const float4* cT4 = (const float4*)cbT;    // cT4[(g*128+d)*256 + t] = dims d of codes 4t..4t+3
  const float* c2g = c2 + g * KCODES;
  for (int i = 0; i < n; ++i) {
    const int pr = rl[i];
    if (tid < DC) xrow[tid] = x[(size_t)pr * (GROUPS*DC) + g*DC + tid];
    __syncthreads();
    float x2 = 0.f;                      // identical op order to round-1
    #pragma unroll
    for (int d = 0; d < DC; ++d) x2 = __fadd_rn(x2, __fmul_rn(xrow[d], xrow[d]));
    float4 A0 = {0.f, 0.f, 0.f, 0.f}, A1 = {0.f, 0.f, 0.f, 0.f};
    #pragma unroll
    for (int d = 0; d < 64; ++d) {       // identical two-chain split to round-1
      float4 cv = cT4[(size_t)(g * DC + d) * 256 + tid];
      float xv = xrow[d];
      A0.x = fmaf(xv, cv.x, A0.x); A0.y = fmaf(xv, cv.y, A0.y);
      A0.z = fmaf(xv, cv.z, A0.z); A0.w = fmaf(xv, cv.w, A0.w);
    }
    #pragma unroll
    for (int d = 64; d < DC; ++d) {
      float4 cv = cT4[(size_t)(g * DC + d) * 256 + tid];
      float xv = xrow[d];
      A1.x = fmaf(xv, cv.x, A1.x); A1.y = fmaf(xv, cv.y, A1.y);
      A1.z = fmaf(xv, cv.z, A1.z); A1.w = fmaf(xv, cv.w, A1.w);
    }
    unsigned long long best = ~0ull;
    {
      float xc = __fadd_rn(A0.x, A1.x);
      float dist = __fadd_rn(__fsub_rn(x2, __fmul_rn(2.0f, xc)), c2g[4*tid + 0]);
      unsigned long long key = ((unsigned long long)__float_as_uint(dist) << 32) | (unsigned)(4*tid + 0);
      if (key < best) best = key;
      xc = __fadd_rn(A0.y, A1.y);
      dist = __fadd_rn(__fsub_rn(x2, __fmul_rn(2.0f, xc)), c2g[4*tid + 1]);
      key = ((unsigned long long)__float_as_uint(dist) << 32) | (unsigned)(4*tid + 1);
      if (key < best) best = key;
      xc = __fadd_rn(A0.z, A1.z);
      dist = __fadd_rn(__fsub_rn(x2, __fmul_rn(2.0f, xc)), c2g[4*tid + 2]);
      key = ((unsigned long long)__float_as_uint(dist) << 32) | (unsigned)(4*tid + 2);
      if (key < best) best = key;
      xc = __fadd_rn(A0.w, A1.w);
      dist = __fadd_rn(__fsub_rn(x2, __fmul_rn(2.0f, xc)), c2g[4*tid + 3]);
      key = ((unsigned long long)__float_as_uint(dist) << 32) | (unsigned)(4*tid + 3);
      if (key < best) best = key;
    }
    red[tid] = best;
    __syncthreads();
    for (int off = 128; off > 0; off >>= 1) {
      if (tid < off) { if (red[tid + off] < red[tid]) red[tid] = red[tid + off]; }
      __syncthreads();
    }
    if (tid == 0) results[(size_t)pr * GROUPS + g] = (unsigned)(red[0] & 1023ull);
    __syncthreads();
  }
}

// ---------------- epilogue: gather/write/loss ----------------
__global__ __launch_bounds__(256, 2) void vq_epilogue_kernel(
    const float* __restrict__ x, const float* __restrict__ cb,
    const unsigned* __restrict__ results, float* __restrict__ out,
    float* __restrict__ partials) {
  const int bid = blockIdx.x;
  const int g = bid & 7;
  const int p = (bid >> 3) * 256 + (int)threadIdx.x;
  const float* xp = x + (size_t)p * (GROUPS*DC) + g*DC;
  float xs[DC];
  #pragma unroll
  for (int d = 0; d < DC; d += 4) {
    float4 v = *reinterpret_cast<const float4*>(xp + d);
    xs[d] = v.x; xs[d+1] = v.y; xs[d+2] = v.z; xs[d+3] = v.w;
  }
  const int bestk = (int)(results[(size_t)p * GROUPS + g] & 1023u);
  const float* q = cb + (size_t)g * KCODES * DC + (size_t)bestk * DC;
  float* op = out + (size_t)p * (GROUPS*DC) + g*DC;
  float lsum = 0.f;
  #pragma unroll
  for (int d = 0; d < DC; d += 4) {
    float4 qv = *reinterpret_cast<const float4*>(q + d);
    float4 ov; float e;
    e = __fsub_rn(xs[d+0], qv.x); lsum = __fadd_rn(lsum, __fmul_rn(e, e));
    ov.x = __fadd_rn(xs[d+0], __fsub_rn(qv.x, xs[d+0]));
    e = __fsub_rn(xs[d+1], qv.y); lsum = __fadd_rn(lsum, __fmul_rn(e, e));
    ov.y = __fadd_rn(xs[d+1], __fsub_rn(qv.y, xs[d+1]));
    e = __fsub_rn(xs[d+2], qv.z); lsum = __fadd_rn(lsum, __fmul_rn(e, e));
    ov.z = __fadd_rn(xs[d+2], __fsub_rn(qv.z, xs[d+2]));
    e = __fsub_rn(xs[d+3], qv.w); lsum = __fadd_rn(lsum, __fmul_rn(e, e));
    ov.w = __fadd_rn(xs[d+3], __fsub_rn(qv.w, xs[d+3]));
    *reinterpret_cast<float4*>(op + d) = ov;
  }
  out[(size_t)QSIZE + 2 + (size_t)p * GROUPS + g] = (float)bestk;

  #pragma unroll
  for (int off = 32; off > 0; off >>= 1)
    lsum += __shfl_down(lsum, off, 64);
  __shared__ float wsum[4];
  if ((threadIdx.x & 63) == 0) wsum[threadIdx.x >> 6] = lsum;
  __syncthreads();
  if (threadIdx.x == 0)
    partials[bid] = __fadd_rn(__fadd_rn(wsum[0], wsum[1]),
                              __fadd_rn(wsum[2], wsum[3]));
}

// ---------------- loss: deterministic double reduction ----------------
__global__ void vq_loss_kernel(const float* __restrict__ partials, float* __restrict__ out) {
  __shared__ double sd[256];
  int t = threadIdx.x;
  sd[t] = (double)partials[t] + (double)partials[t + 256];
  __syncthreads();
  for (int off = 128; off > 0; off >>= 1) {
    if (t < off) sd[t] += sd[t + off];
    __syncthreads();
  }
  if (t == 0) {
    float loss = (float)(sd[0] / 16777216.0);
    out[QSIZE]     = loss;
    out[QSIZE + 1] = loss;
  }
}

// ---------------- round-1 fallback (ws too small) ----------------
__global__ __launch_bounds__(256, 2) void vq_main_kernel(
    const float* __restrict__ x, const float* __restrict__ cb,
    const float* __restrict__ c2, float* __restrict__ out,
    float* __restrict__ partials) {
  const int bid = blockIdx.x;
  const int g = bid & 7;
  const int p = (bid >> 3) * 256 + (int)threadIdx.x;
  const float* xp = x + (size_t)p * (GROUPS*DC) + g*DC;
  float xs[DC];
  #pragma unroll
  for (int d = 0; d < DC; d += 4) {
    float4 v = *reinterpret_cast<const float4*>(xp + d);
    xs[d] = v.x; xs[d+1] = v.y; xs[d+2] = v.z; xs[d+3] = v.w;
  }
  float x2 = 0.f;
  #pragma unroll
  for (int d = 0; d < DC; ++d) x2 = __fadd_rn(x2, __fmul_rn(xs[d], xs[d]));
  const float* cg  = cb + (size_t)g * KCODES * DC;
  const float* c2g = c2 + g * KCODES;
  float best = INFINITY;
  int bestk = 0;
  #pragma unroll 2
  for (int k = 0; k < KCODES; ++k) {
    const float* ck = cg + (size_t)k * DC;
    float a0 = 0.f, a1 = 0.f;
    #pragma unroll
    for (int d = 0; d < 64; ++d)  a0 = fmaf(xs[d], ck[d], a0);
    #pragma unroll
    for (int d = 64; d < DC; ++d) a1 = fmaf(xs[d], ck[d], a1);
    float xc = __fadd_rn(a0, a1);
    float dist = __fadd_rn(__fsub_rn(x2, __fmul_rn(2.0f, xc)), c2g[k]);
    if (dist < best) { best = dist; bestk = k; }
  }
  const float* q = cg + (size_t)bestk * DC;
  float* op = out + (size_t)p * (GROUPS*DC) + g*DC;
  float lsum = 0.f;
  #pragma unroll
  for (int d = 0; d < DC; d += 4) {
    float4 qv = *reinterpret_cast<const float4*>(q + d);
    float4 ov; float e;
    e = __fsub_rn(xs[d+0], qv.x); lsum = __fadd_rn(lsum, __fmul_rn(e, e));
    ov.x = __fadd_rn(xs[d+0], __fsub_rn(qv.x, xs[d+0]));
    e = __fsub_rn(xs[d+1], qv.y); lsum = __fadd_rn(lsum, __fmul_rn(e, e));
    ov.y = __fadd_rn(xs[d+1], __fsub_rn(qv.y, xs[d+1]));
    e = __fsub_rn(xs[d+2], qv.z); lsum = __fadd_rn(lsum, __fmul_rn(e, e));
    ov.z = __fadd_rn(xs[d+2], __fsub_rn(qv.z, xs[d+2]));
    e = __fsub_rn(xs[d+3], qv.w); lsum = __fadd_rn(lsum, __fmul_rn(e, e));
    ov.w = __fadd_rn(xs[d+3], __fsub_rn(qv.w, xs[d+3]));
    *reinterpret_cast<float4*>(op + d) = ov;
  }
  out[(size_t)QSIZE + 2 + (size_t)p * GROUPS + g] = (float)bestk;
  #pragma unroll
  for (int off = 32; off > 0; off >>= 1)
    lsum += __shfl_down(lsum, off, 64);
  __shared__ float wsum[4];
  if ((threadIdx.x & 63) == 0) wsum[threadIdx.x >> 6] = lsum;
  __syncthreads();
  if (threadIdx.x == 0)
    partials[bid] = __fadd_rn(__fadd_rn(wsum[0], wsum[1]),
                              __fadd_rn(wsum[2], wsum[3]));
}

__global__ void vq_c2_kernel(const float* __restrict__ cb, float* __restrict__ c2) {
  int j = blockIdx.x * 256 + threadIdx.x;
  const float* c = cb + (size_t)j * DC;
  float s = 0.f;
  #pragma unroll
  for (int d = 0; d < DC; d += 4) {
    float4 v = *reinterpret_cast<const float4*>(c + d);
    s = __fadd_rn(s, __fmul_rn(v.x, v.x));
    s = __fadd_rn(s, __fmul_rn(v.y, v.y));
    s = __fadd_rn(s, __fmul_rn(v.z, v.z));
    s = __fadd_rn(s, __fmul_rn(v.w, v.w));
  }
  c2[j] = s;
}

extern "C" void kernel_launch(void* const* d_in, const int* in_sizes, int n_in,
                              void* d_out, int out_size, void* d_ws, size_t ws_size,
                              hipStream_t stream) {
  const float* x  = (const float*)d_in[0];
  const float* cb = (const float*)d_in[1];
  float* out = (float*)d_out;
  float* partials   = (float*)d_ws;                       // 512 f32
  float* c2         = partials + 512;                     // 8192 f32
  unsigned* cbh     = (unsigned*)(c2 + 8192);             // 524288 u32 (2 MB)
  unsigned* cbl     = cbh + 524288;                       // 524288 u32 (2 MB)
  unsigned* results = cbl + 524288;                       // 131072 u32 (512 KB)
  float* cbT        = (float*)(results + 131072);         // 1048576 f32 (4 MB, 16B-aligned)
  const size_t need = (512 + 8192) * 4 + (size_t)524288 * 4 * 2
                    + (size_t)131072 * 4 + (size_t)1048576 * 4;  // ~8.95 MB
  if (ws_size >= need) {
    vq_prep_kernel<<<32, 256, 0, stream>>>(cb, cbh, cbl, c2, cbT);
    vq_search_kernel<<<2048, 256, 0, stream>>>(
        x, (const unsigned short*)cbh, (const unsigned short*)cbl, c2, results);
    vq_cleanup_kernel<<<512, 256, 0, stream>>>(x, cbT, c2, results);
    vq_epilogue_kernel<<<512, 256, 0, stream>>>(x, cb, results, out, partials);
    vq_loss_kernel<<<1, 256, 0, stream>>>(partials, out);
  } else {
    vq_c2_kernel<<<32, 256, 0, stream>>>(cb, c2);
    vq_main_kernel<<<512, 256, 0, stream>>>(x, cb, c2, out, partials);
    vq_loss_kernel<<<1, 256, 0, stream>>>(partials, out);
  }
}